// Round 8
// baseline (649.208 us; speedup 1.0000x reference)
//
#include <hip/hip_runtime.h>
#include <hip/hip_bf16.h>

// Problem dims (fixed by reference)
#define BATCH 16384
#define TT    64
#define INF   48
#define FF    32
#define TFD   2048   // T*F   (GEMM1 K)
#define THD   8192   // T*H   (GEMM1 N)

typedef __attribute__((ext_vector_type(8))) short bf16x8;
typedef __attribute__((ext_vector_type(4))) short bf16x4;
typedef __attribute__((ext_vector_type(4))) short short4v;
typedef __attribute__((ext_vector_type(4))) float f32x4;

__device__ inline void gload_lds16(const void* g, void* l) {
  __builtin_amdgcn_global_load_lds((const __attribute__((address_space(1))) void*)g,
                                   (__attribute__((address_space(3))) void*)l, 16, 0, 0);
}

__device__ inline f32x4 mfma16x16x16_bf16(bf16x4 a, bf16x4 b, f32x4 c) {
#if __has_builtin(__builtin_amdgcn_mfma_f32_16x16x16bf16_1k)
  return __builtin_amdgcn_mfma_f32_16x16x16bf16_1k(a, b, c, 0, 0, 0);
#else
  asm("v_mfma_f32_16x16x16_bf16 %0, %1, %2, %0" : "+v"(c) : "v"(a), "v"(b));
  return c;
#endif
}

__device__ inline short f32_to_bf16_bits(float x) {
  __hip_bfloat16 h = __float2bfloat16(x);
  return *reinterpret_cast<short*>(&h);
}

// ---------------- prep kernels ----------------

// xsf: fragment-linear X. Slot (g64, t, bi, lane) holds the 16B B-fragment
// chunk for batch-group g64 (64 rows), K-tile t, sub-frag bi, lane:
//   element j: bf16( x[g64*64 + bi*16 + (lane&15)][t][sidx[(lane>>4)*8 + j]] )
// so gemm's xf[bi] load is ONE coalesced 1KB instruction (base + lane*16).
__global__ void gather_cast_frag(const float* __restrict__ x, const int* __restrict__ sidx,
                                 __hip_bfloat16* __restrict__ xsf) {
  __shared__ int sx[FF];
  if (threadIdx.x < FF) sx[threadIdx.x] = sidx[threadIdx.x];
  __syncthreads();
  const int b64 = blockIdx.x >> 2;          // 0..255
  const int tq  = blockIdx.x & 3;           // t-quarter
  for (int it = 0; it < 16; ++it) {
    const int slot = (tq * 16 + it) * 256 + threadIdx.x;   // ((t*4+bi)*64+l)
    const int t  = slot >> 8;
    const int bi = (slot >> 6) & 3;
    const int l  = slot & 63;
    const int lo = l & 15, hi = l >> 4;
    const int row = b64 * 64 + bi * 16 + lo;
    const float* rp = x + ((size_t)row * TT + t) * INF;
    bf16x8 v;
    #pragma unroll
    for (int j = 0; j < 8; ++j) v[j] = f32_to_bf16_bits(rp[sx[hi * 8 + j]]);
    *(bf16x8*)(xsf + ((size_t)b64 * 16384 + slot) * 8) = v;
  }
}

// W1t[n][k] = bf16(W1[k][n]);  W1: [TFD][THD] row-major. ushort4 stores.
__global__ void transpose_w1(const float* __restrict__ W1, __hip_bfloat16* __restrict__ W1t) {
  __shared__ float tile[64][65];
  const int k0 = blockIdx.x * 64;
  const int n0 = blockIdx.y * 64;
  const int tx = threadIdx.x & 63, ty = threadIdx.x >> 6;
  for (int r = ty; r < 64; r += 4)
    tile[r][tx] = W1[(size_t)(k0 + r) * THD + n0 + tx];
  __syncthreads();
  const int rn = threadIdx.x >> 4;          // 0..15
  const int kq = (threadIdx.x & 15) * 4;    // k-quad
  for (int rr = rn; rr < 64; rr += 16) {
    short4v v;
    #pragma unroll
    for (int i = 0; i < 4; ++i) v[i] = f32_to_bf16_bits(tile[kq + i][rr]);
    *(short4v*)(W1t + (size_t)(n0 + rr) * TFD + k0 + kq) = v;
  }
}

// w2t[f][n] = bf16( sum_t W2[n][t*32+f]*weight[t][f] );  beff[f] = bias[f] + sum_t b2[t*32+f]*weight[t][f]
__global__ void make_w2eff(const float* __restrict__ W2, const float* __restrict__ b2,
                           const float* __restrict__ weight, const float* __restrict__ bias,
                           __hip_bfloat16* __restrict__ w2t, float* __restrict__ beff) {
  const int n = blockIdx.x * 8 + (threadIdx.x >> 5);
  const int f = threadIdx.x & 31;
  const float* wr = W2 + (size_t)n * TFD;
  float s = 0.f;
  #pragma unroll 8
  for (int t = 0; t < TT; ++t) s += wr[t * FF + f] * weight[t * FF + f];
  w2t[(size_t)f * THD + n] = __float2bfloat16(s);
  if (blockIdx.x == 0 && threadIdx.x < FF) {
    float sb = bias[f];
    for (int t = 0; t < TT; ++t) sb += b2[t * FF + f] * weight[t * FF + f];
    beff[f] = sb;
  }
}

// ---------------- main fused GEMM ----------------
// 256(batch) x 256(n_w1) tile, 8 waves (2 mq x 4 bq), BK=32.
// W (A-operand) in LDS: 16KB/tile, paired-row 128B rows + XOR chunk swizzle,
// 4-deep buffers (64KB), staged 3 ahead (counted vmcnt, never 0 mid-loop).
// xs (B-operand): coalesced global->reg from fragment-linear xsf, parity
// sets xfA/xfB refilled 2 iters ahead (refill AFTER phase-B MFMA since both
// phases consume xfu).
// K-iter = TWO m201-style phases (T3 regime): per phase
//   {4x ds_read wf || stage/xf issue -> s_barrier -> lgkmcnt(0) ->
//    setprio(1) 16 MFMA setprio(0) -> s_barrier}
// so one wave's LDS reads drain during the barrier wait + other waves' MFMA
// (r7 measured: reads and MFMA were alternating, pipes ~85% serialized).
// vmcnt ledger (unchanged FIFO order vs r7): steady-state drain to 6 =
// {stage(t+3) 2, xf(t+2) 4}; tails t=61 -> 4, t=62 -> 0; prologue 14 -> 8.

__device__ inline void stage_w(char* buf, const __hip_bfloat16* __restrict__ w1t,
                               int n0, int k0, int wid, int l) {
  const int sub = l >> 3;
  const int c   = (l & 7) ^ sub;             // inverse chunk swizzle
  const int h   = c >> 2, kc = c & 3;
  const int r0  = wid * 8 + sub;             // lds row (128B rows, 2 logical rows each)
  const __hip_bfloat16* gw0 = w1t + (size_t)(n0 + 2 * r0 + h) * TFD + k0 + kc * 8;
  const __hip_bfloat16* gw1 = w1t + (size_t)(n0 + 128 + 2 * r0 + h) * TFD + k0 + kc * 8;
  char* lx = buf + wid * 1024;               // wave-uniform base; HW adds lane*16
  gload_lds16(gw0, lx);
  gload_lds16(gw1, lx + 8192);
}

__device__ __forceinline__ void k_iter(char* lds, int t, int n0,
    const char* __restrict__ xbase, const __hip_bfloat16* __restrict__ w1t,
    f32x4 (&acc)[8][4], bf16x8 (&xfu)[4],
    int wbase, int wid, int l) {
  const char* buf = lds + (t & 3) * 16384;

  // ======== phase A: wf m0..3 reads + stage(t+3) | BAR | lgkm0 | MFMA | BAR ========
  bf16x8 wa0 = *(const bf16x8*)(buf + wbase);
  bf16x8 wa1 = *(const bf16x8*)(buf + wbase + 1024);
  bf16x8 wa2 = *(const bf16x8*)(buf + wbase + 2048);
  bf16x8 wa3 = *(const bf16x8*)(buf + wbase + 3072);
  if (t <= 60) stage_w(lds + ((t + 3) & 3) * 16384, w1t, n0, (t + 3) * 32, wid, l);
  __builtin_amdgcn_sched_barrier(0);
  __builtin_amdgcn_s_barrier();
  asm volatile("s_waitcnt lgkmcnt(0)" ::: "memory");
  __builtin_amdgcn_sched_barrier(0);
  __builtin_amdgcn_s_setprio(1);
  #pragma unroll
  for (int bi = 0; bi < 4; ++bi)
    acc[0][bi] = __builtin_amdgcn_mfma_f32_16x16x32_bf16(wa0, xfu[bi], acc[0][bi], 0, 0, 0);
  #pragma unroll
  for (int bi = 0; bi < 4; ++bi)
    acc[1][bi] = __builtin_amdgcn_mfma_f32_16x16x32_bf16(wa1, xfu[bi], acc[1][bi], 0, 0, 0);
  #pragma unroll
  for (int bi = 0; bi < 4; ++bi)
    acc[2][bi] = __builtin_amdgcn_mfma_f32_16x16x32_bf16(wa2, xfu[bi], acc[2][bi], 0, 0, 0);
  #pragma unroll
  for (int bi = 0; bi < 4; ++bi)
    acc[3][bi] = __builtin_amdgcn_mfma_f32_16x16x32_bf16(wa3, xfu[bi], acc[3][bi], 0, 0, 0);
  __builtin_amdgcn_s_setprio(0);
  __builtin_amdgcn_sched_barrier(0);
  __builtin_amdgcn_s_barrier();

  // ======== phase B: wf m4..7 reads | BAR | lgkm0 | MFMA | xf(t+2) | vmcnt | BAR ====
  bf16x8 wb0 = *(const bf16x8*)(buf + wbase + 4096);
  bf16x8 wb1 = *(const bf16x8*)(buf + wbase + 5120);
  bf16x8 wb2 = *(const bf16x8*)(buf + wbase + 6144);
  bf16x8 wb3 = *(const bf16x8*)(buf + wbase + 7168);
  __builtin_amdgcn_sched_barrier(0);
  __builtin_amdgcn_s_barrier();
  asm volatile("s_waitcnt lgkmcnt(0)" ::: "memory");
  __builtin_amdgcn_sched_barrier(0);
  __builtin_amdgcn_s_setprio(1);
  #pragma unroll
  for (int bi = 0; bi < 4; ++bi)
    acc[4][bi] = __builtin_amdgcn_mfma_f32_16x16x32_bf16(wb0, xfu[bi], acc[4][bi], 0, 0, 0);
  #pragma unroll
  for (int bi = 0; bi < 4; ++bi)
    acc[5][bi] = __builtin_amdgcn_mfma_f32_16x16x32_bf16(wb1, xfu[bi], acc[5][bi], 0, 0, 0);
  #pragma unroll
  for (int bi = 0; bi < 4; ++bi)
    acc[6][bi] = __builtin_amdgcn_mfma_f32_16x16x32_bf16(wb2, xfu[bi], acc[6][bi], 0, 0, 0);
  #pragma unroll
  for (int bi = 0; bi < 4; ++bi)
    acc[7][bi] = __builtin_amdgcn_mfma_f32_16x16x32_bf16(wb3, xfu[bi], acc[7][bi], 0, 0, 0);
  __builtin_amdgcn_s_setprio(0);
  __builtin_amdgcn_sched_barrier(0);
  if (t <= 61) {   // refill the JUST-CONSUMED set with tile t+2 (coalesced 1KB loads)
    #pragma unroll
    for (int bi = 0; bi < 4; ++bi)
      xfu[bi] = *(const bf16x8*)(xbase + ((t + 2) * 4 + bi) * 1024);
  }
  __builtin_amdgcn_sched_barrier(0);
  if (t <= 60)      asm volatile("s_waitcnt vmcnt(6)" ::: "memory");
  else if (t == 61) asm volatile("s_waitcnt vmcnt(4)" ::: "memory");
  else              asm volatile("s_waitcnt vmcnt(0)" ::: "memory");
  __builtin_amdgcn_sched_barrier(0);
  __builtin_amdgcn_s_barrier();
  __builtin_amdgcn_sched_barrier(0);
}

__global__ __launch_bounds__(512, 2) void gemm_fused(
    const __hip_bfloat16* __restrict__ xsf,   // fragment-linear X
    const __hip_bfloat16* __restrict__ w1t,   // [THD][TFD]
    const float* __restrict__ b1,             // [THD]
    const __hip_bfloat16* __restrict__ w2t,   // [FF][THD] bf16
    float* __restrict__ partial)              // [8][BATCH][FF]
{
  __shared__ __align__(16) char lds[65536];   // 4 x 16KB W buffers (sm merge overlays later)
  const int tid = threadIdx.x;
  const int wid = tid >> 6, l = tid & 63;
  const int mq = wid >> 2, bq = wid & 3;      // wave: n_w1-half (2) x batch-quarter (4)
  const int lo = l & 15, hi = l >> 4;
  const int rl = lo >> 1;
  const int cofs = (((((lo & 1) << 2) | hi) ^ rl) << 4);
  const int strip = blockIdx.x & 7;           // strip == XCD -> W slice L2-resident
  const int bt = blockIdx.x >> 3;
  const int b0 = bt * 256;

  const int wbase = ((mq << 6) + rl) * 128 + cofs;              // + mi*1024
  // fragment-linear base for this wave's 64-row group; xf[bi]@t = xbase + (t*4+bi)*1024
  const char* xbase = (const char*)xsf + ((size_t)(bt * 4 + bq) * 16384 + l) * 16;

  f32x4 acc2[2][4];                           // emb^T partial: [f-frag][batch-frag]
  #pragma unroll
  for (int fi = 0; fi < 2; ++fi)
    #pragma unroll
    for (int bi = 0; bi < 4; ++bi) { f32x4 z = {0.f,0.f,0.f,0.f}; acc2[fi][bi] = z; }

  for (int s = 0; s < 4; ++s) {
    const int n0 = strip * 1024 + s * 256;

    f32x4 acc[8][4];                          // h^T frags: [n_w1-frag mi][batch-frag bi]
    #pragma unroll
    for (int mi = 0; mi < 8; ++mi)
      #pragma unroll
      for (int bi = 0; bi < 4; ++bi) { f32x4 z = {0.f,0.f,0.f,0.f}; acc[mi][bi] = z; }

    bf16x8 xfA[4], xfB[4];
    // prologue (issue order pinned; vmcnt(8) drains stage0+xfA, leaves 8)
    stage_w(lds, w1t, n0, 0, wid, l);
    __builtin_amdgcn_sched_barrier(0);
    #pragma unroll
    for (int bi = 0; bi < 4; ++bi) xfA[bi] = *(const bf16x8*)(xbase + (0 * 4 + bi) * 1024);
    __builtin_amdgcn_sched_barrier(0);
    stage_w(lds + 16384, w1t, n0, 32, wid, l);
    __builtin_amdgcn_sched_barrier(0);
    #pragma unroll
    for (int bi = 0; bi < 4; ++bi) xfB[bi] = *(const bf16x8*)(xbase + (1 * 4 + bi) * 1024);
    __builtin_amdgcn_sched_barrier(0);
    stage_w(lds + 32768, w1t, n0, 64, wid, l);
    __builtin_amdgcn_sched_barrier(0);
    asm volatile("s_waitcnt vmcnt(8)" ::: "memory");
    __builtin_amdgcn_sched_barrier(0);
    __builtin_amdgcn_s_barrier();
    __builtin_amdgcn_sched_barrier(0);

    for (int tt = 0; tt < 64; tt += 2) {
      k_iter(lds, tt,     n0, xbase, w1t, acc, xfA, wbase, wid, l);
      k_iter(lds, tt + 1, n0, xbase, w1t, acc, xfB, wbase, wid, l);
    }

    // ---- epilogue: bias+relu+pack in regs, GEMM2 on matrix pipe ----
    #pragma unroll
    for (int mi = 0; mi < 8; ++mi) {
      const int nbase = n0 + (mq << 7) + (mi << 4);
      const float4 b1v = *(const float4*)(b1 + nbase + (hi << 2));
      bf16x4 p[4];
      #pragma unroll
      for (int bi = 0; bi < 4; ++bi) {
        bf16x4 pk;
        #pragma unroll
        for (int j = 0; j < 4; ++j) {
          float v = acc[mi][bi][j] + ((const float*)&b1v)[j];
          v = v > 0.f ? v : 0.f;
          pk[j] = f32_to_bf16_bits(v);
        }
        p[bi] = pk;
      }
      bf16x4 a2[2];
      #pragma unroll
      for (int fi = 0; fi < 2; ++fi)
        a2[fi] = *(const bf16x4*)(w2t + (size_t)(fi * 16 + lo) * THD + nbase + (hi << 2));
      #pragma unroll
      for (int fi = 0; fi < 2; ++fi)
        #pragma unroll
        for (int bi = 0; bi < 4; ++bi)
          acc2[fi][bi] = mfma16x16x16_bf16(a2[fi], p[bi], acc2[fi][bi]);
    }
  }

  // ---- merge the two mq-halves via LDS, then store ----
  float* sm = (float*)lds;                    // [256][32] f32 (32KB; buffers dead)
  if (mq == 1) {
    #pragma unroll
    for (int fi = 0; fi < 2; ++fi)
      #pragma unroll
      for (int bi = 0; bi < 4; ++bi)
        *(f32x4*)(sm + ((bq << 6) + (bi << 4) + lo) * 32 + fi * 16 + (hi << 2)) = acc2[fi][bi];
  }
  __syncthreads();
  if (mq == 0) {
    #pragma unroll
    for (int fi = 0; fi < 2; ++fi)
      #pragma unroll
      for (int bi = 0; bi < 4; ++bi) {
        f32x4 other = *(const f32x4*)(sm + ((bq << 6) + (bi << 4) + lo) * 32 + fi * 16 + (hi << 2));
        f32x4 v = acc2[fi][bi] + other;
        *(f32x4*)(partial + ((size_t)strip * BATCH + b0 + (bq << 6) + (bi << 4) + lo) * FF + fi * 16 + (hi << 2)) = v;
      }
  }
}

// out[b][f] = beff[f] + sum_c partial[c][b][f]
__global__ void reduce_partial(const float* __restrict__ partial, const float* __restrict__ beff,
                               float* __restrict__ out) {
  const int idx = blockIdx.x * 256 + threadIdx.x;
  float s = beff[idx & 31];
  #pragma unroll
  for (int c = 0; c < 8; ++c) s += partial[(size_t)c * BATCH * FF + idx];
  out[idx] = s;
}

// ---------------- launch ----------------

extern "C" void kernel_launch(void* const* d_in, const int* in_sizes, int n_in,
                              void* d_out, int out_size, void* d_ws, size_t ws_size,
                              hipStream_t stream) {
  const float* x      = (const float*)d_in[0];
  const float* W1     = (const float*)d_in[1];
  const float* b1     = (const float*)d_in[2];
  const float* W2     = (const float*)d_in[3];
  const float* b2     = (const float*)d_in[4];
  const float* weight = (const float*)d_in[5];
  const float* bias   = (const float*)d_in[6];
  const int*   sidx   = (const int*)d_in[7];

  char* ws = (char*)d_ws;
  // ws layout (bytes):
  //   xsf     [16384][2048] bf16 (frag-linear) : 0 .. 67108864
  //   w1t     [8192][2048]  bf16 :  67108864 .. 100663296
  //   w2t     [32][8192]    bf16 : 100663296 .. 101187584
  //   beff    [32]          f32  : 101187584 .. 101187712
  //   partial [8][16384][32] f32 : 101188608 .. 117965824
  __hip_bfloat16* xsf  = (__hip_bfloat16*)ws;
  __hip_bfloat16* w1t  = (__hip_bfloat16*)(ws + 67108864);
  __hip_bfloat16* w2t  = (__hip_bfloat16*)(ws + 100663296);
  float*          beff = (float*)(ws + 101187584);
  float*          part = (float*)(ws + 101188608);

  hipLaunchKernelGGL(gather_cast_frag, dim3(1024), dim3(256), 0, stream, x, sidx, xsf);
  hipLaunchKernelGGL(transpose_w1, dim3(32, 128), dim3(256), 0, stream, W1, w1t);
  hipLaunchKernelGGL(make_w2eff,   dim3(1024),    dim3(256), 0, stream, W2, b2, weight, bias, w2t, beff);
  hipLaunchKernelGGL(gemm_fused,   dim3(512),     dim3(512), 0, stream, xsf, w1t, b1, w2t, part);
  hipLaunchKernelGGL(reduce_partial, dim3(2048),  dim3(256), 0, stream, part, beff, (float*)d_out);
}

// Round 9
// 614.242 us; speedup vs baseline: 1.0569x; 1.0569x over previous
//
#include <hip/hip_runtime.h>
#include <hip/hip_bf16.h>

// Problem dims (fixed by reference)
#define BATCH 16384
#define TT    64
#define INF   48
#define FF    32
#define TFD   2048   // T*F   (GEMM1 K)
#define THD   8192   // T*H   (GEMM1 N)

typedef __attribute__((ext_vector_type(8))) short bf16x8;
typedef __attribute__((ext_vector_type(4))) short bf16x4;
typedef __attribute__((ext_vector_type(4))) short short4v;
typedef __attribute__((ext_vector_type(4))) float f32x4;

__device__ inline void gload_lds16(const void* g, void* l) {
  __builtin_amdgcn_global_load_lds((const __attribute__((address_space(1))) void*)g,
                                   (__attribute__((address_space(3))) void*)l, 16, 0, 0);
}

__device__ inline f32x4 mfma16x16x16_bf16(bf16x4 a, bf16x4 b, f32x4 c) {
#if __has_builtin(__builtin_amdgcn_mfma_f32_16x16x16bf16_1k)
  return __builtin_amdgcn_mfma_f32_16x16x16bf16_1k(a, b, c, 0, 0, 0);
#else
  asm("v_mfma_f32_16x16x16_bf16 %0, %1, %2, %0" : "+v"(c) : "v"(a), "v"(b));
  return c;
#endif
}

__device__ inline short f32_to_bf16_bits(float x) {
  __hip_bfloat16 h = __float2bfloat16(x);
  return *reinterpret_cast<short*>(&h);
}

// ---------------- prep kernels ----------------

// xsf: fragment-linear X. Slot (g64, t, bi, lane) holds the 16B B-fragment
// chunk for batch-group g64 (64 rows), K-tile t, sub-frag bi, lane:
//   element j: bf16( x[g64*64 + bi*16 + (lane&15)][t][sidx[(lane>>4)*8 + j]] )
// so gemm's xf[bi] load is ONE coalesced 1KB instruction (base + lane*16).
__global__ void gather_cast_frag(const float* __restrict__ x, const int* __restrict__ sidx,
                                 __hip_bfloat16* __restrict__ xsf) {
  __shared__ int sx[FF];
  if (threadIdx.x < FF) sx[threadIdx.x] = sidx[threadIdx.x];
  __syncthreads();
  const int b64 = blockIdx.x >> 2;          // 0..255
  const int tq  = blockIdx.x & 3;           // t-quarter
  for (int it = 0; it < 16; ++it) {
    const int slot = (tq * 16 + it) * 256 + threadIdx.x;   // ((t*4+bi)*64+l)
    const int t  = slot >> 8;
    const int bi = (slot >> 6) & 3;
    const int l  = slot & 63;
    const int lo = l & 15, hi = l >> 4;
    const int row = b64 * 64 + bi * 16 + lo;
    const float* rp = x + ((size_t)row * TT + t) * INF;
    bf16x8 v;
    #pragma unroll
    for (int j = 0; j < 8; ++j) v[j] = f32_to_bf16_bits(rp[sx[hi * 8 + j]]);
    *(bf16x8*)(xsf + ((size_t)b64 * 16384 + slot) * 8) = v;
  }
}

// W1t[n][k] = bf16(W1[k][n]);  W1: [TFD][THD] row-major. ushort4 stores.
__global__ void transpose_w1(const float* __restrict__ W1, __hip_bfloat16* __restrict__ W1t) {
  __shared__ float tile[64][65];
  const int k0 = blockIdx.x * 64;
  const int n0 = blockIdx.y * 64;
  const int tx = threadIdx.x & 63, ty = threadIdx.x >> 6;
  for (int r = ty; r < 64; r += 4)
    tile[r][tx] = W1[(size_t)(k0 + r) * THD + n0 + tx];
  __syncthreads();
  const int rn = threadIdx.x >> 4;          // 0..15
  const int kq = (threadIdx.x & 15) * 4;    // k-quad
  for (int rr = rn; rr < 64; rr += 16) {
    short4v v;
    #pragma unroll
    for (int i = 0; i < 4; ++i) v[i] = f32_to_bf16_bits(tile[kq + i][rr]);
    *(short4v*)(W1t + (size_t)(n0 + rr) * TFD + k0 + kq) = v;
  }
}

// w2t[f][n] = bf16( sum_t W2[n][t*32+f]*weight[t][f] );  beff[f] = bias[f] + sum_t b2[t*32+f]*weight[t][f]
__global__ void make_w2eff(const float* __restrict__ W2, const float* __restrict__ b2,
                           const float* __restrict__ weight, const float* __restrict__ bias,
                           __hip_bfloat16* __restrict__ w2t, float* __restrict__ beff) {
  const int n = blockIdx.x * 8 + (threadIdx.x >> 5);
  const int f = threadIdx.x & 31;
  const float* wr = W2 + (size_t)n * TFD;
  float s = 0.f;
  #pragma unroll 8
  for (int t = 0; t < TT; ++t) s += wr[t * FF + f] * weight[t * FF + f];
  w2t[(size_t)f * THD + n] = __float2bfloat16(s);
  if (blockIdx.x == 0 && threadIdx.x < FF) {
    float sb = bias[f];
    for (int t = 0; t < TT; ++t) sb += b2[t * FF + f] * weight[t * FF + f];
    beff[f] = sb;
  }
}

// ---------------- main fused GEMM ----------------
// 256(batch) x 256(n_w1) tile, 8 waves (2 mq x 4 bq), BK=32.
// r9 change vs r7: 8 LDS buffers (128KB) + s_barrier only every SECOND
// K-iter. Rationale: acc regs (128) + arch VGPR (128) = ~256/wave ->
// 2 waves/SIMD, ONE block/CU; the per-iter barrier locksteps all 8 waves
// so fetch (TCP ~768cyc + LDS ~640cyc) serializes with MFMA (1242cyc).
// Sparser barriers let SIMD-mates drift anti-phase within a 2-iter window.
// Safety (per-wave vmcnt ledger unchanged): end-of-iter-u drain to 6 leaves
// {stage(u+3), xf(u+2)} => stage(u+2) COMPLETE. Reader of buffer t&7 passed
// a barrier that the producer passed only after its iter >= t-2 wait, i.e.
// after stage(t) completed. Writes in a window hit (t+3..t+4)&7, reads
// {t,t+1}&7: mod-8 distance 2..4, disjoint.
// vmcnt ledger: steady drain to 6; tails t=61 -> 4, t=62 -> 0; prologue 14->8.

__device__ inline void stage_w(char* buf, const __hip_bfloat16* __restrict__ w1t,
                               int n0, int k0, int wid, int l) {
  const int sub = l >> 3;
  const int c   = (l & 7) ^ sub;             // inverse chunk swizzle
  const int h   = c >> 2, kc = c & 3;
  const int r0  = wid * 8 + sub;             // lds row (128B rows, 2 logical rows each)
  const __hip_bfloat16* gw0 = w1t + (size_t)(n0 + 2 * r0 + h) * TFD + k0 + kc * 8;
  const __hip_bfloat16* gw1 = w1t + (size_t)(n0 + 128 + 2 * r0 + h) * TFD + k0 + kc * 8;
  char* lx = buf + wid * 1024;               // wave-uniform base; HW adds lane*16
  gload_lds16(gw0, lx);
  gload_lds16(gw1, lx + 8192);
}

__device__ __forceinline__ void k_iter(char* lds, int t, int n0,
    const char* __restrict__ xbase, const __hip_bfloat16* __restrict__ w1t,
    f32x4 (&acc)[8][4], bf16x8 (&xfu)[4],
    int wbase, int wid, int l, bool do_bar) {
  if (t <= 60) stage_w(lds + ((t + 3) & 7) * 16384, w1t, n0, (t + 3) * 32, wid, l);
  __builtin_amdgcn_sched_barrier(0);
  const char* buf = lds + (t & 7) * 16384;
  bf16x8 w0  = *(const bf16x8*)(buf + wbase);
  bf16x8 w1f = *(const bf16x8*)(buf + wbase + 1024);
  #pragma unroll
  for (int g = 0; g < 4; ++g) {
    bf16x8 nw0, nw1;
    if (g < 3) {
      nw0 = *(const bf16x8*)(buf + wbase + (2 * g + 2) * 1024);
      nw1 = *(const bf16x8*)(buf + wbase + (2 * g + 3) * 1024);
    }
    __builtin_amdgcn_s_setprio(1);
    #pragma unroll
    for (int bi = 0; bi < 4; ++bi)
      acc[2 * g][bi] = __builtin_amdgcn_mfma_f32_16x16x32_bf16(w0, xfu[bi], acc[2 * g][bi], 0, 0, 0);
    #pragma unroll
    for (int bi = 0; bi < 4; ++bi)
      acc[2 * g + 1][bi] = __builtin_amdgcn_mfma_f32_16x16x32_bf16(w1f, xfu[bi], acc[2 * g + 1][bi], 0, 0, 0);
    __builtin_amdgcn_s_setprio(0);
    if (g < 3) { w0 = nw0; w1f = nw1; }
  }
  if (t <= 61) {   // refill the JUST-CONSUMED set with tile t+2 (coalesced 1KB loads)
    #pragma unroll
    for (int bi = 0; bi < 4; ++bi)
      xfu[bi] = *(const bf16x8*)(xbase + ((t + 2) * 4 + bi) * 1024);
  }
  __builtin_amdgcn_sched_barrier(0);
  if (t <= 60)      asm volatile("s_waitcnt vmcnt(6)" ::: "memory");
  else if (t == 61) asm volatile("s_waitcnt vmcnt(4)" ::: "memory");
  else              asm volatile("s_waitcnt vmcnt(0)" ::: "memory");
  __builtin_amdgcn_sched_barrier(0);
  if (do_bar) {
    __builtin_amdgcn_s_barrier();
    __builtin_amdgcn_sched_barrier(0);
  }
}

__global__ __launch_bounds__(512, 2) void gemm_fused(
    const __hip_bfloat16* __restrict__ xsf,   // fragment-linear X
    const __hip_bfloat16* __restrict__ w1t,   // [THD][TFD]
    const float* __restrict__ b1,             // [THD]
    const __hip_bfloat16* __restrict__ w2t,   // [FF][THD] bf16
    float* __restrict__ partial)              // [8][BATCH][FF]
{
  __shared__ __align__(16) char lds[131072];  // 8 x 16KB W buffers
  const int tid = threadIdx.x;
  const int wid = tid >> 6, l = tid & 63;
  const int mq = wid >> 2, bq = wid & 3;      // wave: n_w1-half (2) x batch-quarter (4)
  const int lo = l & 15, hi = l >> 4;
  const int rl = lo >> 1;
  const int cofs = (((((lo & 1) << 2) | hi) ^ rl) << 4);
  const int strip = blockIdx.x & 7;           // strip == XCD -> W slice L2-resident
  const int bt = blockIdx.x >> 3;
  const int b0 = bt * 256;

  const int wbase = ((mq << 6) + rl) * 128 + cofs;              // + mi*1024
  // fragment-linear base for this wave's 64-row group; xf[bi]@t = xbase + (t*4+bi)*1024
  const char* xbase = (const char*)xsf + ((size_t)(bt * 4 + bq) * 16384 + l) * 16;

  f32x4 acc2[2][4];                           // emb^T partial: [f-frag][batch-frag]
  #pragma unroll
  for (int fi = 0; fi < 2; ++fi)
    #pragma unroll
    for (int bi = 0; bi < 4; ++bi) { f32x4 z = {0.f,0.f,0.f,0.f}; acc2[fi][bi] = z; }

  for (int s = 0; s < 4; ++s) {
    const int n0 = strip * 1024 + s * 256;

    f32x4 acc[8][4];                          // h^T frags: [n_w1-frag mi][batch-frag bi]
    #pragma unroll
    for (int mi = 0; mi < 8; ++mi)
      #pragma unroll
      for (int bi = 0; bi < 4; ++bi) { f32x4 z = {0.f,0.f,0.f,0.f}; acc[mi][bi] = z; }

    bf16x8 xfA[4], xfB[4];
    // prologue (issue order pinned; vmcnt(8) drains stage0+xfA, leaves 8)
    stage_w(lds, w1t, n0, 0, wid, l);
    __builtin_amdgcn_sched_barrier(0);
    #pragma unroll
    for (int bi = 0; bi < 4; ++bi) xfA[bi] = *(const bf16x8*)(xbase + (0 * 4 + bi) * 1024);
    __builtin_amdgcn_sched_barrier(0);
    stage_w(lds + 16384, w1t, n0, 32, wid, l);
    __builtin_amdgcn_sched_barrier(0);
    #pragma unroll
    for (int bi = 0; bi < 4; ++bi) xfB[bi] = *(const bf16x8*)(xbase + (1 * 4 + bi) * 1024);
    __builtin_amdgcn_sched_barrier(0);
    stage_w(lds + 32768, w1t, n0, 64, wid, l);
    __builtin_amdgcn_sched_barrier(0);
    asm volatile("s_waitcnt vmcnt(8)" ::: "memory");
    __builtin_amdgcn_sched_barrier(0);
    __builtin_amdgcn_s_barrier();
    __builtin_amdgcn_sched_barrier(0);

    for (int tt = 0; tt < 64; tt += 2) {
      k_iter(lds, tt,     n0, xbase, w1t, acc, xfA, wbase, wid, l, false);
      k_iter(lds, tt + 1, n0, xbase, w1t, acc, xfB, wbase, wid, l, true);
    }

    // ---- epilogue: bias+relu+pack in regs, GEMM2 on matrix pipe ----
    #pragma unroll
    for (int mi = 0; mi < 8; ++mi) {
      const int nbase = n0 + (mq << 7) + (mi << 4);
      const float4 b1v = *(const float4*)(b1 + nbase + (hi << 2));
      bf16x4 p[4];
      #pragma unroll
      for (int bi = 0; bi < 4; ++bi) {
        bf16x4 pk;
        #pragma unroll
        for (int j = 0; j < 4; ++j) {
          float v = acc[mi][bi][j] + ((const float*)&b1v)[j];
          v = v > 0.f ? v : 0.f;
          pk[j] = f32_to_bf16_bits(v);
        }
        p[bi] = pk;
      }
      bf16x4 a2[2];
      #pragma unroll
      for (int fi = 0; fi < 2; ++fi)
        a2[fi] = *(const bf16x4*)(w2t + (size_t)(fi * 16 + lo) * THD + nbase + (hi << 2));
      #pragma unroll
      for (int fi = 0; fi < 2; ++fi)
        #pragma unroll
        for (int bi = 0; bi < 4; ++bi)
          acc2[fi][bi] = mfma16x16x16_bf16(a2[fi], p[bi], acc2[fi][bi]);
    }
  }

  // ---- merge the two mq-halves via LDS, then store ----
  float* sm = (float*)lds;                    // [256][32] f32 (32KB; buffers dead)
  if (mq == 1) {
    #pragma unroll
    for (int fi = 0; fi < 2; ++fi)
      #pragma unroll
      for (int bi = 0; bi < 4; ++bi)
        *(f32x4*)(sm + ((bq << 6) + (bi << 4) + lo) * 32 + fi * 16 + (hi << 2)) = acc2[fi][bi];
  }
  __syncthreads();
  if (mq == 0) {
    #pragma unroll
    for (int fi = 0; fi < 2; ++fi)
      #pragma unroll
      for (int bi = 0; bi < 4; ++bi) {
        f32x4 other = *(const f32x4*)(sm + ((bq << 6) + (bi << 4) + lo) * 32 + fi * 16 + (hi << 2));
        f32x4 v = acc2[fi][bi] + other;
        *(f32x4*)(partial + ((size_t)strip * BATCH + b0 + (bq << 6) + (bi << 4) + lo) * FF + fi * 16 + (hi << 2)) = v;
      }
  }
}

// out[b][f] = beff[f] + sum_c partial[c][b][f]
__global__ void reduce_partial(const float* __restrict__ partial, const float* __restrict__ beff,
                               float* __restrict__ out) {
  const int idx = blockIdx.x * 256 + threadIdx.x;
  float s = beff[idx & 31];
  #pragma unroll
  for (int c = 0; c < 8; ++c) s += partial[(size_t)c * BATCH * FF + idx];
  out[idx] = s;
}

// ---------------- launch ----------------

extern "C" void kernel_launch(void* const* d_in, const int* in_sizes, int n_in,
                              void* d_out, int out_size, void* d_ws, size_t ws_size,
                              hipStream_t stream) {
  const float* x      = (const float*)d_in[0];
  const float* W1     = (const float*)d_in[1];
  const float* b1     = (const float*)d_in[2];
  const float* W2     = (const float*)d_in[3];
  const float* b2     = (const float*)d_in[4];
  const float* weight = (const float*)d_in[5];
  const float* bias   = (const float*)d_in[6];
  const int*   sidx   = (const int*)d_in[7];

  char* ws = (char*)d_ws;
  // ws layout (bytes):
  //   xsf     [16384][2048] bf16 (frag-linear) : 0 .. 67108864
  //   w1t     [8192][2048]  bf16 :  67108864 .. 100663296
  //   w2t     [32][8192]    bf16 : 100663296 .. 101187584
  //   beff    [32]          f32  : 101187584 .. 101187712
  //   partial [8][16384][32] f32 : 101188608 .. 117965824
  __hip_bfloat16* xsf  = (__hip_bfloat16*)ws;
  __hip_bfloat16* w1t  = (__hip_bfloat16*)(ws + 67108864);
  __hip_bfloat16* w2t  = (__hip_bfloat16*)(ws + 100663296);
  float*          beff = (float*)(ws + 101187584);
  float*          part = (float*)(ws + 101188608);

  hipLaunchKernelGGL(gather_cast_frag, dim3(1024), dim3(256), 0, stream, x, sidx, xsf);
  hipLaunchKernelGGL(transpose_w1, dim3(32, 128), dim3(256), 0, stream, W1, w1t);
  hipLaunchKernelGGL(make_w2eff,   dim3(1024),    dim3(256), 0, stream, W2, b2, weight, bias, w2t, beff);
  hipLaunchKernelGGL(gemm_fused,   dim3(512),     dim3(512), 0, stream, xsf, w1t, b1, w2t, part);
  hipLaunchKernelGGL(reduce_partial, dim3(2048),  dim3(256), 0, stream, part, beff, (float*)d_out);
}